// Round 13
// baseline (233.118 us; speedup 1.0000x reference)
//
#include <hip/hip_runtime.h>
#include <math.h>

#define D_MODEL 512
#define NHEADS  8
#define DHEAD   64

typedef __bf16  bf16x2 __attribute__((ext_vector_type(2)));
typedef __bf16  bf16x4 __attribute__((ext_vector_type(4)));
typedef __bf16  bf16x8 __attribute__((ext_vector_type(8)));
typedef float   f32x4  __attribute__((ext_vector_type(4)));
typedef float   f32x16 __attribute__((ext_vector_type(16)));

#define QSCALE 0.18033688f   /* 0.125 * log2(e): softmax runs in exp2 domain */
#define DEFER_THR 11.5416f   /* 8 nats in log2 units */

// global -> LDS direct copy, 16B per lane. LDS dest = wave-uniform base + lane*16.
__device__ __forceinline__ void gload16(const __bf16* g, __bf16* l) {
    __builtin_amdgcn_global_load_lds(
        (const __attribute__((address_space(1))) unsigned int*)g,
        (__attribute__((address_space(3))) unsigned int*)l, 16, 0, 0);
}

// ---------------------------------------------------------------------------
// Transpose+convert: src [K][N] fp32 -> dst [N][K] bf16.  64x64 LDS tile.
// ---------------------------------------------------------------------------
__device__ __forceinline__ void transpose_tile(
        const float* __restrict__ src, __bf16* __restrict__ dst,
        int K, int N, int k0, int n0) {
    __shared__ float t[64][65];
    int tid = threadIdx.x;
    int r = tid >> 6, c = tid & 63;
#pragma unroll
    for (int i = 0; i < 16; ++i)
        t[r + 4 * i][c] = src[(size_t)(k0 + r + 4 * i) * N + n0 + c];
    __syncthreads();
#pragma unroll
    for (int i = 0; i < 16; ++i)
        dst[(size_t)(n0 + r + 4 * i) * K + k0 + c] = (__bf16)t[c][r + 4 * i];
}

// ---------------------------------------------------------------------------
// Merged prep: adaln params GEMV + 10 weight transposes + cond fp32->bf16.
// ---------------------------------------------------------------------------
struct PrepArgs {
    const float *t, *n1w, *n1b, *n2w, *n2b, *n4w, *n4b;
    float* emb;
    const float* ws[8]; __bf16* wd[8];
    const float *ffw1, *ffw2;
    __bf16 *ff1t, *ff2t;
    const float* cond; __bf16* cbf;
    int B, condN;
};

__global__ __launch_bounds__(256) void prep_kernel(PrepArgs a) {
    int bb = blockIdx.x, tid = threadIdx.x;
    if (bb < 24) {
        int gI = bb * 256 + tid;
        int per = a.B * 2 * D_MODEL;
        if (gI >= 3 * per) return;
        int norm = gI / per;
        int rem  = gI - norm * per;
        int b = rem / (2 * D_MODEL);
        int c = rem % (2 * D_MODEL);
        const float* W  = (norm == 0) ? a.n1w : (norm == 1 ? a.n2w : a.n4w);
        const float* bb_= (norm == 0) ? a.n1b : (norm == 1 ? a.n2b : a.n4b);
        const float* trow = a.t + (size_t)b * D_MODEL;
        float acc = bb_[c];
        for (int k = 0; k < D_MODEL; ++k)
            acc = fmaf(trow[k], W[(size_t)k * (2 * D_MODEL) + c], acc);
        a.emb[gI] = acc;
    } else if (bb < 536) {
        int w = (bb - 24) >> 6, tI = (bb - 24) & 63;
        transpose_tile(a.ws[w], a.wd[w], 512, 512, (tI >> 3) << 6, (tI & 7) << 6);
    } else if (bb < 1048) {
        int tI = bb - 536;
        transpose_tile(a.ffw1, a.ff1t, 512, 4096, (tI & 7) << 6, (tI >> 3) << 6);
    } else if (bb < 1304) {
        int tI = bb - 1048;
        transpose_tile(a.ffw2, a.ff2t, 2048, 512, (tI >> 3) << 6, (tI & 7) << 6);
    } else {
        int i = ((bb - 1304) * 256 + tid) * 4;
        if (i >= a.condN) return;
        float4 v = *(const float4*)(a.cond + i);
        bf16x2 p0, p1;
        p0[0] = (__bf16)v.x; p0[1] = (__bf16)v.y;
        p1[0] = (__bf16)v.z; p1[1] = (__bf16)v.w;
        *(bf16x2*)(a.cbf + i)     = p0;
        *(bf16x2*)(a.cbf + i + 2) = p1;
    }
}

// ---------------------------------------------------------------------------
// AdaLN apply -> bf16 output. Block per row (512 cols, 2 per thread).
// ---------------------------------------------------------------------------
__global__ __launch_bounds__(256) void adaln_apply_kernel(
        const float* __restrict__ x, const float* __restrict__ emb_n,
        __bf16* __restrict__ h, int N) {
    int row = blockIdx.x;
    int b = row / N;
    const float* xr = x + (size_t)row * D_MODEL;
    int tid = threadIdx.x;
    float2 v = *(const float2*)(xr + 2 * tid);
    float s = v.x + v.y, sq = v.x * v.x + v.y * v.y;
#pragma unroll
    for (int off = 32; off; off >>= 1) {
        s  += __shfl_xor(s, off);
        sq += __shfl_xor(sq, off);
    }
    __shared__ float rs[4], rq[4];
    if ((tid & 63) == 0) { rs[tid >> 6] = s; rq[tid >> 6] = sq; }
    __syncthreads();
    float tot  = rs[0] + rs[1] + rs[2] + rs[3];
    float totq = rq[0] + rq[1] + rq[2] + rq[3];
    float mu  = tot * (1.0f / D_MODEL);
    float var = totq * (1.0f / D_MODEL) - mu * mu;
    float inv = rsqrtf(var + 1e-5f);
    const float* er = emb_n + (size_t)b * (2 * D_MODEL);
    float2 sc = *(const float2*)(er + 2 * tid);
    float2 sh = *(const float2*)(er + D_MODEL + 2 * tid);
    bf16x2 o;
    o[0] = (__bf16)((v.x - mu) * inv * (1.0f + sc.x) + sh.x);
    o[1] = (__bf16)((v.y - mu) * inv * (1.0f + sc.y) + sh.y);
    *(bf16x2*)(h + (size_t)row * D_MODEL + 2 * tid) = o;
}

// ---------------------------------------------------------------------------
// bf16 MFMA GEMM body (m97 structure). C = A[M,K] @ Bt[N,K]^T.
// OUT=0: bf16. OUT=1: fp32 + bias + res. OUT=2: bf16, cols<512 scaled QSCALE.
// ---------------------------------------------------------------------------
template<int OUT, int WM>
__device__ __forceinline__ void gemm_body(
        const __bf16* __restrict__ A, const __bf16* __restrict__ Bt,
        const float* __restrict__ bias, const float* __restrict__ res,
        void* __restrict__ Cv, int M, int K, int N, int bx, int by,
        __bf16* As, __bf16* Bs) {
    constexpr int MI = WM / 16;
    int tid = threadIdx.x;
    int wave = tid >> 6, lane = tid & 63;
    int wr = wave >> 1, wc = wave & 1;
    int r = lane & 15, g = lane >> 4;
    int rx = r & 7;
    int m0 = by * (2 * WM), n0 = bx << 6;

    int lrow = lane >> 3;
    int lcol = ((lane & 7) ^ lrow) << 3;
    const __bf16* Ag = A  + (size_t)(m0 + (wave << 3) + lrow) * K + lcol;
    const __bf16* Bg = Bt + (size_t)(n0 + (wave << 3) + lrow) * K + lcol;
    __bf16* AsW = As + (size_t)(wave << 3) * 64;
    __bf16* BsW = Bs + (size_t)(wave << 3) * 64;

    f32x4 acc[MI][2];
#pragma unroll
    for (int mi = 0; mi < MI; ++mi)
#pragma unroll
        for (int ni = 0; ni < 2; ++ni) acc[mi][ni] = (f32x4){0.f, 0.f, 0.f, 0.f};

    for (int k0 = 0; k0 < K; k0 += 64) {
        if (k0) __syncthreads();
#pragma unroll
        for (int i = 0; i < MI; ++i)
            gload16(Ag + (size_t)(i * 32) * K + k0, AsW + i * 32 * 64);
#pragma unroll
        for (int j = 0; j < 2; ++j)
            gload16(Bg + (size_t)(j * 32) * K + k0, BsW + j * 32 * 64);
        __syncthreads();
#pragma unroll
        for (int kk = 0; kk < 2; ++kk) {
            int cs = ((((kk << 2) + g) ^ rx) << 3);
            bf16x8 af[MI], bf_[2];
#pragma unroll
            for (int mi = 0; mi < MI; ++mi)
                af[mi] = *(const bf16x8*)&As[(size_t)(wr * WM + (mi << 4) + r) * 64 + cs];
#pragma unroll
            for (int ni = 0; ni < 2; ++ni)
                bf_[ni] = *(const bf16x8*)&Bs[(size_t)((wc << 5) + (ni << 4) + r) * 64 + cs];
#pragma unroll
            for (int mi = 0; mi < MI; ++mi)
#pragma unroll
                for (int ni = 0; ni < 2; ++ni)
                    acc[mi][ni] = __builtin_amdgcn_mfma_f32_16x16x32_bf16(
                        af[mi], bf_[ni], acc[mi][ni], 0, 0, 0);
        }
    }

#pragma unroll
    for (int mi = 0; mi < MI; ++mi) {
#pragma unroll
        for (int ni = 0; ni < 2; ++ni) {
            int col = n0 + (wc << 5) + (ni << 4) + r;
            float scl = (OUT == 2 && col < 512) ? QSCALE : 1.0f;
#pragma unroll
            for (int rg = 0; rg < 4; ++rg) {
                int row = m0 + wr * WM + (mi << 4) + (g << 2) + rg;
                if (OUT == 1) {
                    float v = acc[mi][ni][rg] + bias[col] + res[(size_t)row * N + col];
                    ((float*)Cv)[(size_t)row * N + col] = v;
                } else {
                    ((__bf16*)Cv)[(size_t)row * N + col] = (__bf16)(acc[mi][ni][rg] * scl);
                }
            }
        }
    }
}

template<int OUT, int WM>
__global__ __launch_bounds__(256) void gemm_bf16_kernel(
        const __bf16* __restrict__ A, const __bf16* __restrict__ Bt,
        const float* __restrict__ bias, const float* __restrict__ res,
        void* __restrict__ Cv, int M, int K, int N) {
    __shared__ __attribute__((aligned(16))) __bf16 As[2 * WM * 64];
    __shared__ __attribute__((aligned(16))) __bf16 Bs[64 * 64];
    gemm_body<OUT, WM>(A, Bt, bias, res, Cv, M, K, N, blockIdx.x, blockIdx.y, As, Bs);
}

// q2 (OUT=2) and kv2 (OUT=0) fused in one dispatch.
__global__ __launch_bounds__(256) void gemm_dual_kernel(
        const __bf16* A0, const __bf16* B0, __bf16* C0, int M0,
        const __bf16* A1, const __bf16* B1, __bf16* C1, int M1) {
    __shared__ __attribute__((aligned(16))) __bf16 As[64 * 64];
    __shared__ __attribute__((aligned(16))) __bf16 Bs[64 * 64];
    int nb0 = 8 * (M0 >> 6);
    if ((int)blockIdx.x < nb0) {
        gemm_body<2, 32>(A0, B0, nullptr, nullptr, C0, M0, 512, 512,
                         blockIdx.x & 7, blockIdx.x >> 3, As, Bs);
    } else {
        int id = blockIdx.x - nb0;
        gemm_body<0, 32>(A1, B1, nullptr, nullptr, C1, M1, 512, 1024,
                         id & 15, id >> 4, As, Bs);
    }
}

// ---------------------------------------------------------------------------
// Fused GEGLU FF1 (bf16 MFMA, round-6 proven shape): gg[M,2048] = u * gelu(g)
// ---------------------------------------------------------------------------
__global__ __launch_bounds__(256) void gemm_geglu_bf16_kernel(
        const __bf16* __restrict__ A, const __bf16* __restrict__ W1t,
        const float* __restrict__ b1, __bf16* __restrict__ gg, int M, int K) {
    const int NOUT = 4 * D_MODEL;   // 2048
    __shared__ __attribute__((aligned(16))) __bf16 AsL[128 * 64];
    __shared__ __attribute__((aligned(16))) __bf16 BuL[64 * 64];
    __shared__ __attribute__((aligned(16))) __bf16 BgL[64 * 64];
    int tid = threadIdx.x;
    int wave = tid >> 6, lane = tid & 63;
    int wr = wave >> 1, wc = wave & 1;
    int r = lane & 15, g = lane >> 4;
    int rx = r & 7;
    int m0 = blockIdx.y << 7, n0 = blockIdx.x << 6;

    int lrow = lane >> 3;
    int lcol = ((lane & 7) ^ lrow) << 3;
    const __bf16* Ag = A   + (size_t)(m0 + (wave << 3) + lrow) * K + lcol;
    const __bf16* Ug = W1t + (size_t)(n0 + (wave << 3) + lrow) * K + lcol;
    const __bf16* Gg = W1t + (size_t)(NOUT + n0 + (wave << 3) + lrow) * K + lcol;
    __bf16* AsW = AsL + (size_t)(wave << 3) * 64;
    __bf16* BuW = BuL + (size_t)(wave << 3) * 64;
    __bf16* BgW = BgL + (size_t)(wave << 3) * 64;

    f32x4 accu[4][2], accg[4][2];
#pragma unroll
    for (int mi = 0; mi < 4; ++mi)
#pragma unroll
        for (int ni = 0; ni < 2; ++ni) {
            accu[mi][ni] = (f32x4){0.f, 0.f, 0.f, 0.f};
            accg[mi][ni] = (f32x4){0.f, 0.f, 0.f, 0.f};
        }

    for (int k0 = 0; k0 < K; k0 += 64) {
        if (k0) __syncthreads();
#pragma unroll
        for (int i = 0; i < 4; ++i)
            gload16(Ag + (size_t)(i * 32) * K + k0, AsW + i * 32 * 64);
#pragma unroll
        for (int j = 0; j < 2; ++j) {
            gload16(Ug + (size_t)(j * 32) * K + k0, BuW + j * 32 * 64);
            gload16(Gg + (size_t)(j * 32) * K + k0, BgW + j * 32 * 64);
        }
        __syncthreads();
#pragma unroll
        for (int kk = 0; kk < 2; ++kk) {
            int cs = ((((kk << 2) + g) ^ rx) << 3);
            bf16x8 af[4], bu[2], bg[2];
#pragma unroll
            for (int mi = 0; mi < 4; ++mi)
                af[mi] = *(const bf16x8*)&AsL[(size_t)((wr << 6) + (mi << 4) + r) * 64 + cs];
#pragma unroll
            for (int ni = 0; ni < 2; ++ni) {
                bu[ni] = *(const bf16x8*)&BuL[(size_t)((wc << 5) + (ni << 4) + r) * 64 + cs];
                bg[ni] = *(const bf16x8*)&BgL[(size_t)((wc << 5) + (ni << 4) + r) * 64 + cs];
            }
#pragma unroll
            for (int mi = 0; mi < 4; ++mi)
#pragma unroll
                for (int ni = 0; ni < 2; ++ni) {
                    accu[mi][ni] = __builtin_amdgcn_mfma_f32_16x16x32_bf16(
                        af[mi], bu[ni], accu[mi][ni], 0, 0, 0);
                    accg[mi][ni] = __builtin_amdgcn_mfma_f32_16x16x32_bf16(
                        af[mi], bg[ni], accg[mi][ni], 0, 0, 0);
                }
        }
    }

#pragma unroll
    for (int mi = 0; mi < 4; ++mi) {
#pragma unroll
        for (int ni = 0; ni < 2; ++ni) {
            int col = n0 + (wc << 5) + (ni << 4) + r;
            float bu_ = b1[col], bg_ = b1[NOUT + col];
#pragma unroll
            for (int rg = 0; rg < 4; ++rg) {
                int row = m0 + (wr << 6) + (mi << 4) + (g << 2) + rg;
                float u  = accu[mi][ni][rg] + bu_;
                float gv = accg[mi][ni][rg] + bg_;
                float ge = 0.5f * gv * (1.0f + erff(gv * 0.70710678118654752f));
                gg[(size_t)row * NOUT + col] = (__bf16)(u * ge);
            }
        }
    }
}

// ---------------------------------------------------------------------------
// bf16 MFMA flash attention v7: 32x32x16 fragments (r12-verified layouts),
// 8 waves x 32 q-rows = 256-row Q-tile, split-KV (blockIdx.y) for grid=256,
// role-split staging (tid<256: V, tid>=256: K), widened XOR swizzle
// ((row&7)^(row>>3)) on Ks/Vt/Pl, exp2 softmax + defer-max, T1 XCD swizzle.
// Writes UNNORMALIZED partial O + per-row (m,l); attn_merge combines.
// Q must be pre-scaled by 0.125*log2(e).
// ---------------------------------------------------------------------------
__global__ __launch_bounds__(512) void attn_mfma_kernel(
        const __bf16* __restrict__ q, const __bf16* __restrict__ k,
        const __bf16* __restrict__ v, __bf16* __restrict__ op0,
        __bf16* __restrict__ op1, float* __restrict__ ml,
        int Nq, int Nk, int sq, int skv) {
    __shared__ __attribute__((aligned(16))) __bf16 Ks[2][4096];  // [key][64d] swz
    __shared__ __attribute__((aligned(16))) __bf16 Vt[2][4096];  // [dim][64key] swz
    __shared__ __attribute__((aligned(16))) __bf16 Pl[8][2048];  // per-wave [32q][64key] swz

    int tid = threadIdx.x;
    int w = tid >> 6, lane = tid & 63;
    int c = lane & 31;          // q-row within wave / MFMA column
    int hg = lane >> 5;         // k-group half
    int cx = c & 7;
    int sxp = cx ^ (c >> 3);    // Pl swizzle term

    // T1 XCD-chunked swizzle (grid.x = 128, multiple of 8)
    int nwg = gridDim.x;
    int cpx = nwg >> 3;
    int bid = (int)blockIdx.x;
    int lb  = (bid & 7) * cpx + (bid >> 3);

    int split = blockIdx.y;
    int kvlen = Nk >> 1;

    int nqb = Nq >> 8;
    int qb = lb % nqb;
    int hh = (lb / nqb) % NHEADS;
    int b  = lb / (nqb * NHEADS);

    // Q B-fragments: qf[ks][j] = Q[qrow=c][d = ks*16 + hg*8 + j]
    const __bf16* qp = q + ((size_t)(b * Nq + (qb << 8) + (w << 5) + c)) * sq
                         + hh * DHEAD + (hg << 3);
    bf16x8 qf[4];
#pragma unroll
    for (int ks = 0; ks < 4; ++ks) qf[ks] = *(const bf16x8*)(qp + ks * 16);

    // staging roles: tid<256 -> V, tid>=256 -> K (round-9 verified maps + wider xor)
    bool isK = (tid >= 256);
    int sidx = tid & 255;
    int krow = sidx >> 2, kp_ = sidx & 3;
    int va = sidx & 31, vbb = sidx >> 5;
    size_t kvbase = (size_t)b * Nk * skv + (size_t)hh * DHEAD
                  + (size_t)split * kvlen * skv;
    const __bf16* kp = k + kvbase + (size_t)krow * skv + (kp_ << 4);
    const __bf16* vp = v + kvbase + (size_t)(2 * va) * skv + (vbb << 3);
    int ksx  = (krow & 7) ^ (krow >> 3);
    int kwo0 = krow * 64 + ((((kp_ << 1) | 0) ^ ksx) << 3);
    int kwo1 = krow * 64 + ((((kp_ << 1) | 1) ^ ksx) << 3);

    f32x16 oacc[2];
#pragma unroll
    for (int db = 0; db < 2; ++db)
#pragma unroll
        for (int rg = 0; rg < 16; ++rg) oacc[db][rg] = 0.f;
    float m = -1e30f, l = 0.f;
    f32x16 saccA[2], saccB[2];
    bf16x8 sr0, sr1;
    bf16x8 vf[2][4], pb[4];

    auto LOADREG = [&](int t) {
        if (isK) {
            const __bf16* kp2 = kp + (size_t)t * 64 * skv;
            sr0 = *(const bf16x8*)kp2; sr1 = *(const bf16x8*)(kp2 + 8);
        } else {
            const __bf16* vp2 = vp + (size_t)t * 64 * skv;
            sr0 = *(const bf16x8*)vp2; sr1 = *(const bf16x8*)(vp2 + skv);
        }
    };
    auto STAGEW = [&](int buf) {
        if (isK) {
            *(bf16x8*)&Ks[buf][kwo0] = sr0;
            *(bf16x8*)&Ks[buf][kwo1] = sr1;
        } else {
#pragma unroll
            for (int j = 0; j < 8; ++j) {
                bf16x2 pr; pr[0] = sr0[j]; pr[1] = sr1[j];
                *(bf16x2*)&Vt[buf][vbb * 512 + j * 64
                                   + ((((va >> 2) ^ j ^ vbb) & 7) << 3)
                                   + ((va & 3) << 1)] = pr;
            }
        }
    };
    auto QKT = [&](f32x16 (&sacc)[2], int buf) {
#pragma unroll
        for (int kb = 0; kb < 2; ++kb)
#pragma unroll
            for (int rg = 0; rg < 16; ++rg) sacc[kb][rg] = 0.f;
        __builtin_amdgcn_s_setprio(1);
#pragma unroll
        for (int kb = 0; kb < 2; ++kb) {
            int row = (kb << 5) + c;
            int sxk = cx ^ (((kb << 2) + (c >> 3)) & 7);
#pragma unroll
            for (int ks = 0; ks < 4; ++ks) {
                bf16x8 kf = *(const bf16x8*)&Ks[buf][row * 64
                                + ((((ks << 1) + hg) ^ sxk) << 3)];
                sacc[kb] = __builtin_amdgcn_mfma_f32_32x32x16_bf16(
                    kf, qf[ks], sacc[kb], 0, 0, 0);
            }
        }
        __builtin_amdgcn_s_setprio(0);
    };
    auto SMAX = [&](f32x16 (&sacc)[2]) {
        float mx = sacc[0][0];
#pragma unroll
        for (int kb = 0; kb < 2; ++kb)
#pragma unroll
            for (int rg = 0; rg < 16; ++rg) mx = fmaxf(mx, sacc[kb][rg]);
        mx = fmaxf(mx, __shfl_xor(mx, 32));
        if (!__all(mx <= m + DEFER_THR)) {
            float mn = fmaxf(m, mx);
            float al = exp2f(m - mn);
            m = mn; l *= al;
#pragma unroll
            for (int db = 0; db < 2; ++db)
#pragma unroll
                for (int rg = 0; rg < 16; ++rg) oacc[db][rg] *= al;
        }
        float sum = 0.f;
#pragma unroll
        for (int kb = 0; kb < 2; ++kb) {
#pragma unroll
            for (int rg4 = 0; rg4 < 4; ++rg4) {
                bf16x4 pk;
#pragma unroll
                for (int rr = 0; rr < 4; ++rr) {
                    float p = exp2f(sacc[kb][(rg4 << 2) + rr] - m);
                    sum += p;
                    pk[rr] = (__bf16)p;
                }
                int slot = (kb << 2) + rg4;   // key = 8*slot + 4*hg + rr
                *(bf16x4*)&Pl[w][c * 64 + ((slot ^ sxp) << 3) + (hg << 2)] = pk;
            }
        }
        l += sum;   // per-lane partial; lane^32 holds complementary keys
    };
    auto VFLOAD = [&](int buf) {
#pragma unroll
        for (int ks = 0; ks < 4; ++ks)
            pb[ks] = *(const bf16x8*)&Pl[w][c * 64 + ((((ks << 1) + hg) ^ sxp) << 3)];
#pragma unroll
        for (int db = 0; db < 2; ++db) {
            int row = (db << 5) + c;
            int sxv = cx ^ (((db << 2) + (c >> 3)) & 7);
#pragma unroll
            for (int ks = 0; ks < 4; ++ks)
                vf[db][ks] = *(const bf16x8*)&Vt[buf][row * 64
                                + ((((ks << 1) + hg) ^ sxv) << 3)];
        }
    };
    auto PVOP = [&]() {
        __builtin_amdgcn_s_setprio(1);
#pragma unroll
        for (int db = 0; db < 2; ++db)
#pragma unroll
            for (int ks = 0; ks < 4; ++ks)
                oacc[db] = __builtin_amdgcn_mfma_f32_32x32x16_bf16(
                    vf[db][ks], pb[ks], oacc[db], 0, 0, 0);
        __builtin_amdgcn_s_setprio(0);
    };

    int ntiles = kvlen >> 6;   // self 16, cross 8: even
    // ---- prologue ----------------------------------------------------------
    LOADREG(0);
    STAGEW(0);
    LOADREG(1);
    __syncthreads();
    QKT(saccA, 0);

    for (int t = 0; t + 1 < ntiles; t += 2) {
        // ---- even phase: tile t (buf0, saccA); regs hold t+1 ----------------
        STAGEW(1);
        if (t + 2 < ntiles) LOADREG(t + 2);
        SMAX(saccA);
        VFLOAD(0);
        __syncthreads();
        QKT(saccB, 1);
        PVOP();
        // ---- odd phase: tile t+1 (buf1, saccB); regs hold t+2 ---------------
        if (t + 2 < ntiles) {
            STAGEW(0);
            if (t + 3 < ntiles) LOADREG(t + 3);
        }
        SMAX(saccB);
        VFLOAD(1);
        __syncthreads();
        if (t + 2 < ntiles) QKT(saccA, 0);
        PVOP();
    }

    // ---- epilogue: finish l; write UNNORMALIZED O + (m,l) -------------------
    l += __shfl_xor(l, 32);
    int rowq = (qb << 8) + (w << 5) + c;
    __bf16* ob = (split ? op1 : op0)
               + ((size_t)(b * Nq + rowq)) * D_MODEL + hh * DHEAD;
#pragma unroll
    for (int db = 0; db < 2; ++db) {
#pragma unroll
        for (int rg4 = 0; rg4 < 4; ++rg4) {
            bf16x4 ov;
#pragma unroll
            for (int rr = 0; rr < 4; ++rr)
                ov[rr] = (__bf16)oacc[db][(rg4 << 2) + rr];
            *(bf16x4*)&ob[(db << 5) + (rg4 << 3) + (hg << 2)] = ov;
        }
    }
    if (hg == 0) {
        size_t mi_ = ((((size_t)(b * NHEADS + hh) * Nq + rowq) << 1) + split) << 1;
        ml[mi_]     = m;
        ml[mi_ + 1] = l;
    }
}

// ---------------------------------------------------------------------------
// Merge two KV-split attention partials: out = (a0*O0 + a1*O1)/(a0*l0 + a1*l1)
// ---------------------------------------------------------------------------
__global__ __launch_bounds__(256) void attn_merge_kernel(
        const __bf16* __restrict__ p0, const __bf16* __restrict__ p1,
        const float* __restrict__ ml, __bf16* __restrict__ out, int Nq) {
    int i = blockIdx.x * 256 + threadIdx.x;      // octet id over B*Nq*64
    int oct = i & 63, rowg = i >> 6;             // rowg in [0, B*Nq)
    int b = rowg / Nq, row = rowg - b * Nq;
    int h = oct >> 3;
    size_t mb = (((size_t)(b * NHEADS + h) * Nq + row) << 2);
    float m0 = ml[mb], l0 = ml[mb + 1], m1 = ml[mb + 2], l1 = ml[mb + 3];
    float mm = fmaxf(m0, m1);
    float a0 = exp2f(m0 - mm), a1 = exp2f(m1 - mm);
    float inv = 1.0f / (a0 * l0 + a1 * l1);
    a0 *= inv; a1 *= inv;
    size_t off = (size_t)rowg * D_MODEL + oct * 8;
    bf16x8 x0 = *(const bf16x8*)(p0 + off);
    bf16x8 x1 = *(const bf16x8*)(p1 + off);
    bf16x8 o;
#pragma unroll
    for (int j = 0; j < 8; ++j)
        o[j] = (__bf16)(a0 * (float)x0[j] + a1 * (float)x1[j]);
    *(bf16x8*)(out + off) = o;
}

// ---------------------------------------------------------------------------
extern "C" void kernel_launch(void* const* d_in, const int* in_sizes, int n_in,
                              void* d_out, int out_size, void* d_ws, size_t ws_size,
                              hipStream_t stream) {
    const float* x    = (const float*)d_in[0];
    const float* t    = (const float*)d_in[1];
    const float* cond = (const float*)d_in[2];
    const float* n1_w = (const float*)d_in[3];
    const float* n1_b = (const float*)d_in[4];
    const float* n2_w = (const float*)d_in[5];
    const float* n2_b = (const float*)d_in[6];
    const float* n4_w = (const float*)d_in[7];
    const float* n4_b = (const float*)d_in[8];
    const float* a1_q = (const float*)d_in[9];
    const float* a1_k = (const float*)d_in[10];
    const float* a1_v = (const float*)d_in[11];
    const float* a1_o = (const float*)d_in[12];
    const float* a1_ob= (const float*)d_in[13];
    const float* a2_q = (const float*)d_in[14];
    const float* a2_k = (const float*)d_in[15];
    const float* a2_v = (const float*)d_in[16];
    const float* a2_o = (const float*)d_in[17];
    const float* a2_ob= (const float*)d_in[18];
    const float* ff_w1= (const float*)d_in[19];
    const float* ff_b1= (const float*)d_in[20];
    const float* ff_w2= (const float*)d_in[21];
    const float* ff_b2= (const float*)d_in[22];
    float* out = (float*)d_out;

    const int B  = in_sizes[1] / D_MODEL;              // 2
    const int N  = in_sizes[0] / (B * D_MODEL);        // 2048
    const int Nc = in_sizes[2] / (B * D_MODEL);        // 1024
    const int R  = B * N;                              // 4096
    const int Rc = B * Nc;                             // 2048

    // ---- workspace layout (~33.4 MB peak) --------------------------------------
    char* Wb = (char*)d_ws;
    float* emb   = (float*)Wb;                                   // 32 KB
    __bf16* r1   = (__bf16*)(Wb + 32768);                        // 16 MiB region
    __bf16* qkv  = r1;                                           // [R][1536]
    __bf16* q2   = r1;                                           // [R][512]
    __bf16* kv2  = r1 + (size_t)R * 512;                         // [Rc][1024]
    __bf16* gg   = r1;                                           // [R][2048]
    __bf16* p0s  = r1 + (size_t)R * 1536;                        // self split0 (4 MiB)
    __bf16* p0c  = r1 + (size_t)4 * 1048576;                     // cross split0 (4 MiB)
    __bf16* p1c  = r1 + (size_t)6 * 1048576;                     // cross split1 (4 MiB)
    __bf16* h_bf = (__bf16*)(Wb + 32768 + 16777216);             // 4 MiB (attn out / p1 self)
    __bf16* c_bf = (__bf16*)(Wb + 32768 + 16777216 + 4194304);   // 2 MiB
    __bf16* wts  = (__bf16*)(Wb + 32768 + 16777216 + 4194304 + 2097152);
    __bf16* a1_qt = wts;                      // contiguous q,k,v -> fused QKV Bt
    __bf16* a1_ot = wts + 3 * 262144;
    __bf16* a2_qt = wts + 4 * 262144;
    __bf16* a2_kt = wts + 5 * 262144;         // contiguous k,v -> fused KV Bt
    __bf16* a2_ot = wts + 7 * 262144;
    __bf16* ff1t  = wts + 8 * 262144;         // [4096][512]
    __bf16* ff2t  = ff1t + 2097152;           // [512][2048]
    float* mlbuf = (float*)(Wb + 32768 + 16777216 + 4194304 + 2097152 + 10485760);
                                              // [B][H][N][2][2] fp32 = 512 KiB

    dim3 blk(256);

    // ---- single merged prep dispatch -------------------------------------------
    PrepArgs pa;
    pa.t = t; pa.n1w = n1_w; pa.n1b = n1_b; pa.n2w = n2_w; pa.n2b = n2_b;
    pa.n4w = n4_w; pa.n4b = n4_b; pa.emb = emb;
    pa.ws[0] = a1_q; pa.ws[1] = a1_k; pa.ws[2] = a1_v; pa.ws[3] = a1_o;
    pa.ws[4] = a2_q; pa.ws[5] = a2_k; pa.ws[6] = a2_v; pa.ws[7] = a2_o;
    pa.wd[0] = a1_qt; pa.wd[1] = wts + 262144; pa.wd[2] = wts + 2 * 262144; pa.wd[3] = a1_ot;
    pa.wd[4] = a2_qt; pa.wd[5] = a2_kt; pa.wd[6] = wts + 6 * 262144; pa.wd[7] = a2_ot;
    pa.ffw1 = ff_w1; pa.ffw2 = ff_w2; pa.ff1t = ff1t; pa.ff2t = ff2t;
    pa.cond = cond; pa.cbf = c_bf; pa.B = B; pa.condN = Rc * D_MODEL;
    prep_kernel<<<dim3(1304 + (Rc * D_MODEL) / 1024), blk, 0, stream>>>(pa);

    // ---- block 1: self-attention -----------------------------------------------
    adaln_apply_kernel<<<dim3(R), blk, 0, stream>>>(x, emb, h_bf, N);
    gemm_bf16_kernel<2, 64><<<dim3(24, R / 128), blk, 0, stream>>>(
        h_bf, a1_qt, nullptr, nullptr, qkv, R, 512, 1536);
    attn_mfma_kernel<<<dim3(B * NHEADS * (N / 256), 2), dim3(512), 0, stream>>>(
        qkv, qkv + 512, qkv + 1024, p0s, h_bf, mlbuf, N, N, 1536, 1536);
    attn_merge_kernel<<<dim3(R * 64 / 256), blk, 0, stream>>>(
        p0s, h_bf, mlbuf, h_bf, N);
    gemm_bf16_kernel<1, 32><<<dim3(8, R / 64), blk, 0, stream>>>(
        h_bf, a1_ot, a1_ob, x, out, R, 512, 512);

    // ---- block 2: cross-attention ------------------------------------------------
    adaln_apply_kernel<<<dim3(R), blk, 0, stream>>>(
        out, emb + (size_t)B * 2 * D_MODEL, h_bf, N);
    gemm_dual_kernel<<<dim3(8 * (R / 64) + 16 * (Rc / 64)), blk, 0, stream>>>(
        h_bf, a2_qt, q2, R, c_bf, a2_kt, kv2, Rc);
    attn_mfma_kernel<<<dim3(B * NHEADS * (N / 256), 2), dim3(512), 0, stream>>>(
        q2, kv2, kv2 + 512, p0c, p1c, mlbuf, N, Nc, 512, 1024);
    attn_merge_kernel<<<dim3(R * 64 / 256), blk, 0, stream>>>(
        p0c, p1c, mlbuf, h_bf, N);
    gemm_bf16_kernel<1, 32><<<dim3(8, R / 64), blk, 0, stream>>>(
        h_bf, a2_ot, a2_ob, out, out, R, 512, 512);

    // ---- GEGLU feed-forward ---------------------------------------------------------
    adaln_apply_kernel<<<dim3(R), blk, 0, stream>>>(
        out, emb + (size_t)2 * B * 2 * D_MODEL, h_bf, N);
    gemm_geglu_bf16_kernel<<<dim3(32, R / 128), blk, 0, stream>>>(
        h_bf, ff1t, ff_b1, gg, R, 512);
    gemm_bf16_kernel<1, 32><<<dim3(8, R / 64), blk, 0, stream>>>(
        gg, ff2t, ff_b2, out, out, R, 2048, 512);
}

// Round 14
// 210.859 us; speedup vs baseline: 1.1056x; 1.1056x over previous
//
#include <hip/hip_runtime.h>
#include <math.h>

#define D_MODEL 512
#define NHEADS  8
#define DHEAD   64

typedef __bf16  bf16x2 __attribute__((ext_vector_type(2)));
typedef __bf16  bf16x4 __attribute__((ext_vector_type(4)));
typedef __bf16  bf16x8 __attribute__((ext_vector_type(8)));
typedef float   f32x4  __attribute__((ext_vector_type(4)));

#define QSCALE 0.18033688f   /* 0.125 * log2(e): softmax runs in exp2 domain */
#define DEFER_THR 11.5416f   /* 8 nats in log2 units */

// global -> LDS direct copy, 16B per lane. LDS dest = wave-uniform base + lane*16.
__device__ __forceinline__ void gload16(const __bf16* g, __bf16* l) {
    __builtin_amdgcn_global_load_lds(
        (const __attribute__((address_space(1))) unsigned int*)g,
        (__attribute__((address_space(3))) unsigned int*)l, 16, 0, 0);
}

// ---------------------------------------------------------------------------
// Transpose+convert: src [K][N] fp32 -> dst [N][K] bf16.  64x64 LDS tile.
// ---------------------------------------------------------------------------
__device__ __forceinline__ void transpose_tile(
        const float* __restrict__ src, __bf16* __restrict__ dst,
        int K, int N, int k0, int n0) {
    __shared__ float t[64][65];
    int tid = threadIdx.x;
    int r = tid >> 6, c = tid & 63;
#pragma unroll
    for (int i = 0; i < 16; ++i)
        t[r + 4 * i][c] = src[(size_t)(k0 + r + 4 * i) * N + n0 + c];
    __syncthreads();
#pragma unroll
    for (int i = 0; i < 16; ++i)
        dst[(size_t)(n0 + r + 4 * i) * K + k0 + c] = (__bf16)t[c][r + 4 * i];
}

// ---------------------------------------------------------------------------
// Merged prep: adaln params GEMV + 10 weight transposes + cond fp32->bf16.
// ---------------------------------------------------------------------------
struct PrepArgs {
    const float *t, *n1w, *n1b, *n2w, *n2b, *n4w, *n4b;
    float* emb;
    const float* ws[8]; __bf16* wd[8];
    const float *ffw1, *ffw2;
    __bf16 *ff1t, *ff2t;
    const float* cond; __bf16* cbf;
    int B, condN;
};

__global__ __launch_bounds__(256) void prep_kernel(PrepArgs a) {
    int bb = blockIdx.x, tid = threadIdx.x;
    if (bb < 24) {
        int gI = bb * 256 + tid;
        int per = a.B * 2 * D_MODEL;
        if (gI >= 3 * per) return;
        int norm = gI / per;
        int rem  = gI - norm * per;
        int b = rem / (2 * D_MODEL);
        int c = rem % (2 * D_MODEL);
        const float* W  = (norm == 0) ? a.n1w : (norm == 1 ? a.n2w : a.n4w);
        const float* bb_= (norm == 0) ? a.n1b : (norm == 1 ? a.n2b : a.n4b);
        const float* trow = a.t + (size_t)b * D_MODEL;
        float acc = bb_[c];
        for (int k = 0; k < D_MODEL; ++k)
            acc = fmaf(trow[k], W[(size_t)k * (2 * D_MODEL) + c], acc);
        a.emb[gI] = acc;
    } else if (bb < 536) {
        int w = (bb - 24) >> 6, tI = (bb - 24) & 63;
        transpose_tile(a.ws[w], a.wd[w], 512, 512, (tI >> 3) << 6, (tI & 7) << 6);
    } else if (bb < 1048) {
        int tI = bb - 536;
        transpose_tile(a.ffw1, a.ff1t, 512, 4096, (tI & 7) << 6, (tI >> 3) << 6);
    } else if (bb < 1304) {
        int tI = bb - 1048;
        transpose_tile(a.ffw2, a.ff2t, 2048, 512, (tI >> 3) << 6, (tI & 7) << 6);
    } else {
        int i = ((bb - 1304) * 256 + tid) * 4;
        if (i >= a.condN) return;
        float4 v = *(const float4*)(a.cond + i);
        bf16x2 p0, p1;
        p0[0] = (__bf16)v.x; p0[1] = (__bf16)v.y;
        p1[0] = (__bf16)v.z; p1[1] = (__bf16)v.w;
        *(bf16x2*)(a.cbf + i)     = p0;
        *(bf16x2*)(a.cbf + i + 2) = p1;
    }
}

// ---------------------------------------------------------------------------
// AdaLN apply -> bf16 output. Block per row (512 cols, 2 per thread).
// ---------------------------------------------------------------------------
__global__ __launch_bounds__(256) void adaln_apply_kernel(
        const float* __restrict__ x, const float* __restrict__ emb_n,
        __bf16* __restrict__ h, int N) {
    int row = blockIdx.x;
    int b = row / N;
    const float* xr = x + (size_t)row * D_MODEL;
    int tid = threadIdx.x;
    float2 v = *(const float2*)(xr + 2 * tid);
    float s = v.x + v.y, sq = v.x * v.x + v.y * v.y;
#pragma unroll
    for (int off = 32; off; off >>= 1) {
        s  += __shfl_xor(s, off);
        sq += __shfl_xor(sq, off);
    }
    __shared__ float rs[4], rq[4];
    if ((tid & 63) == 0) { rs[tid >> 6] = s; rq[tid >> 6] = sq; }
    __syncthreads();
    float tot  = rs[0] + rs[1] + rs[2] + rs[3];
    float totq = rq[0] + rq[1] + rq[2] + rq[3];
    float mu  = tot * (1.0f / D_MODEL);
    float var = totq * (1.0f / D_MODEL) - mu * mu;
    float inv = rsqrtf(var + 1e-5f);
    const float* er = emb_n + (size_t)b * (2 * D_MODEL);
    float2 sc = *(const float2*)(er + 2 * tid);
    float2 sh = *(const float2*)(er + D_MODEL + 2 * tid);
    bf16x2 o;
    o[0] = (__bf16)((v.x - mu) * inv * (1.0f + sc.x) + sh.x);
    o[1] = (__bf16)((v.y - mu) * inv * (1.0f + sc.y) + sh.y);
    *(bf16x2*)(h + (size_t)row * D_MODEL + 2 * tid) = o;
}

// ---------------------------------------------------------------------------
// bf16 MFMA GEMM body (m97 structure). C = A[M,K] @ Bt[N,K]^T.
// OUT=0: bf16. OUT=1: fp32 + bias + res. OUT=2: bf16, cols<512 scaled QSCALE.
// ---------------------------------------------------------------------------
template<int OUT, int WM>
__device__ __forceinline__ void gemm_body(
        const __bf16* __restrict__ A, const __bf16* __restrict__ Bt,
        const float* __restrict__ bias, const float* __restrict__ res,
        void* __restrict__ Cv, int M, int K, int N, int bx, int by,
        __bf16* As, __bf16* Bs) {
    constexpr int MI = WM / 16;
    int tid = threadIdx.x;
    int wave = tid >> 6, lane = tid & 63;
    int wr = wave >> 1, wc = wave & 1;
    int r = lane & 15, g = lane >> 4;
    int rx = r & 7;
    int m0 = by * (2 * WM), n0 = bx << 6;

    int lrow = lane >> 3;
    int lcol = ((lane & 7) ^ lrow) << 3;
    const __bf16* Ag = A  + (size_t)(m0 + (wave << 3) + lrow) * K + lcol;
    const __bf16* Bg = Bt + (size_t)(n0 + (wave << 3) + lrow) * K + lcol;
    __bf16* AsW = As + (size_t)(wave << 3) * 64;
    __bf16* BsW = Bs + (size_t)(wave << 3) * 64;

    f32x4 acc[MI][2];
#pragma unroll
    for (int mi = 0; mi < MI; ++mi)
#pragma unroll
        for (int ni = 0; ni < 2; ++ni) acc[mi][ni] = (f32x4){0.f, 0.f, 0.f, 0.f};

    for (int k0 = 0; k0 < K; k0 += 64) {
        if (k0) __syncthreads();
#pragma unroll
        for (int i = 0; i < MI; ++i)
            gload16(Ag + (size_t)(i * 32) * K + k0, AsW + i * 32 * 64);
#pragma unroll
        for (int j = 0; j < 2; ++j)
            gload16(Bg + (size_t)(j * 32) * K + k0, BsW + j * 32 * 64);
        __syncthreads();
#pragma unroll
        for (int kk = 0; kk < 2; ++kk) {
            int cs = ((((kk << 2) + g) ^ rx) << 3);
            bf16x8 af[MI], bf_[2];
#pragma unroll
            for (int mi = 0; mi < MI; ++mi)
                af[mi] = *(const bf16x8*)&As[(size_t)(wr * WM + (mi << 4) + r) * 64 + cs];
#pragma unroll
            for (int ni = 0; ni < 2; ++ni)
                bf_[ni] = *(const bf16x8*)&Bs[(size_t)((wc << 5) + (ni << 4) + r) * 64 + cs];
#pragma unroll
            for (int mi = 0; mi < MI; ++mi)
#pragma unroll
                for (int ni = 0; ni < 2; ++ni)
                    acc[mi][ni] = __builtin_amdgcn_mfma_f32_16x16x32_bf16(
                        af[mi], bf_[ni], acc[mi][ni], 0, 0, 0);
        }
    }

#pragma unroll
    for (int mi = 0; mi < MI; ++mi) {
#pragma unroll
        for (int ni = 0; ni < 2; ++ni) {
            int col = n0 + (wc << 5) + (ni << 4) + r;
            float scl = (OUT == 2 && col < 512) ? QSCALE : 1.0f;
#pragma unroll
            for (int rg = 0; rg < 4; ++rg) {
                int row = m0 + wr * WM + (mi << 4) + (g << 2) + rg;
                if (OUT == 1) {
                    float v = acc[mi][ni][rg] + bias[col] + res[(size_t)row * N + col];
                    ((float*)Cv)[(size_t)row * N + col] = v;
                } else {
                    ((__bf16*)Cv)[(size_t)row * N + col] = (__bf16)(acc[mi][ni][rg] * scl);
                }
            }
        }
    }
}

template<int OUT, int WM>
__global__ __launch_bounds__(256) void gemm_bf16_kernel(
        const __bf16* __restrict__ A, const __bf16* __restrict__ Bt,
        const float* __restrict__ bias, const float* __restrict__ res,
        void* __restrict__ Cv, int M, int K, int N) {
    __shared__ __attribute__((aligned(16))) __bf16 As[2 * WM * 64];
    __shared__ __attribute__((aligned(16))) __bf16 Bs[64 * 64];
    gemm_body<OUT, WM>(A, Bt, bias, res, Cv, M, K, N, blockIdx.x, blockIdx.y, As, Bs);
}

// q2 (OUT=2) and kv2 (OUT=0) fused in one dispatch.
__global__ __launch_bounds__(256) void gemm_dual_kernel(
        const __bf16* A0, const __bf16* B0, __bf16* C0, int M0,
        const __bf16* A1, const __bf16* B1, __bf16* C1, int M1) {
    __shared__ __attribute__((aligned(16))) __bf16 As[64 * 64];
    __shared__ __attribute__((aligned(16))) __bf16 Bs[64 * 64];
    int nb0 = 8 * (M0 >> 6);
    if ((int)blockIdx.x < nb0) {
        gemm_body<2, 32>(A0, B0, nullptr, nullptr, C0, M0, 512, 512,
                         blockIdx.x & 7, blockIdx.x >> 3, As, Bs);
    } else {
        int id = blockIdx.x - nb0;
        gemm_body<0, 32>(A1, B1, nullptr, nullptr, C1, M1, 512, 1024,
                         id & 15, id >> 4, As, Bs);
    }
}

// ---------------------------------------------------------------------------
// Fused GEGLU FF1 (bf16 MFMA, round-6 proven shape): gg[M,2048] = u * gelu(g)
// ---------------------------------------------------------------------------
__global__ __launch_bounds__(256) void gemm_geglu_bf16_kernel(
        const __bf16* __restrict__ A, const __bf16* __restrict__ W1t,
        const float* __restrict__ b1, __bf16* __restrict__ gg, int M, int K) {
    const int NOUT = 4 * D_MODEL;   // 2048
    __shared__ __attribute__((aligned(16))) __bf16 AsL[128 * 64];
    __shared__ __attribute__((aligned(16))) __bf16 BuL[64 * 64];
    __shared__ __attribute__((aligned(16))) __bf16 BgL[64 * 64];
    int tid = threadIdx.x;
    int wave = tid >> 6, lane = tid & 63;
    int wr = wave >> 1, wc = wave & 1;
    int r = lane & 15, g = lane >> 4;
    int rx = r & 7;
    int m0 = blockIdx.y << 7, n0 = blockIdx.x << 6;

    int lrow = lane >> 3;
    int lcol = ((lane & 7) ^ lrow) << 3;
    const __bf16* Ag = A   + (size_t)(m0 + (wave << 3) + lrow) * K + lcol;
    const __bf16* Ug = W1t + (size_t)(n0 + (wave << 3) + lrow) * K + lcol;
    const __bf16* Gg = W1t + (size_t)(NOUT + n0 + (wave << 3) + lrow) * K + lcol;
    __bf16* AsW = AsL + (size_t)(wave << 3) * 64;
    __bf16* BuW = BuL + (size_t)(wave << 3) * 64;
    __bf16* BgW = BgL + (size_t)(wave << 3) * 64;

    f32x4 accu[4][2], accg[4][2];
#pragma unroll
    for (int mi = 0; mi < 4; ++mi)
#pragma unroll
        for (int ni = 0; ni < 2; ++ni) {
            accu[mi][ni] = (f32x4){0.f, 0.f, 0.f, 0.f};
            accg[mi][ni] = (f32x4){0.f, 0.f, 0.f, 0.f};
        }

    for (int k0 = 0; k0 < K; k0 += 64) {
        if (k0) __syncthreads();
#pragma unroll
        for (int i = 0; i < 4; ++i)
            gload16(Ag + (size_t)(i * 32) * K + k0, AsW + i * 32 * 64);
#pragma unroll
        for (int j = 0; j < 2; ++j) {
            gload16(Ug + (size_t)(j * 32) * K + k0, BuW + j * 32 * 64);
            gload16(Gg + (size_t)(j * 32) * K + k0, BgW + j * 32 * 64);
        }
        __syncthreads();
#pragma unroll
        for (int kk = 0; kk < 2; ++kk) {
            int cs = ((((kk << 2) + g) ^ rx) << 3);
            bf16x8 af[4], bu[2], bg[2];
#pragma unroll
            for (int mi = 0; mi < 4; ++mi)
                af[mi] = *(const bf16x8*)&AsL[(size_t)((wr << 6) + (mi << 4) + r) * 64 + cs];
#pragma unroll
            for (int ni = 0; ni < 2; ++ni) {
                bu[ni] = *(const bf16x8*)&BuL[(size_t)((wc << 5) + (ni << 4) + r) * 64 + cs];
                bg[ni] = *(const bf16x8*)&BgL[(size_t)((wc << 5) + (ni << 4) + r) * 64 + cs];
            }
#pragma unroll
            for (int mi = 0; mi < 4; ++mi)
#pragma unroll
                for (int ni = 0; ni < 2; ++ni) {
                    accu[mi][ni] = __builtin_amdgcn_mfma_f32_16x16x32_bf16(
                        af[mi], bu[ni], accu[mi][ni], 0, 0, 0);
                    accg[mi][ni] = __builtin_amdgcn_mfma_f32_16x16x32_bf16(
                        af[mi], bg[ni], accg[mi][ni], 0, 0, 0);
                }
        }
    }

#pragma unroll
    for (int mi = 0; mi < 4; ++mi) {
#pragma unroll
        for (int ni = 0; ni < 2; ++ni) {
            int col = n0 + (wc << 5) + (ni << 4) + r;
            float bu_ = b1[col], bg_ = b1[NOUT + col];
#pragma unroll
            for (int rg = 0; rg < 4; ++rg) {
                int row = m0 + (wr << 6) + (mi << 4) + (g << 2) + rg;
                float u  = accu[mi][ni][rg] + bu_;
                float gv = accg[mi][ni][rg] + bg_;
                float ge = 0.5f * gv * (1.0f + erff(gv * 0.70710678118654752f));
                gg[(size_t)row * NOUT + col] = (__bf16)(u * ge);
            }
        }
    }
}

// ---------------------------------------------------------------------------
// bf16 MFMA flash attention v4 (round-9 verified best): QBLK=128 / 8 waves.
// Staging role-split: waves 0-3 stage V (verified swizzle map), waves 4-7
// stage K (verified map) -> each K/V tile staged ONCE per 128 q-rows.
// Swapped operands, exp2-domain softmax, double-buffered K/V (1 barrier/tile),
// uniform XOR-16B swizzle, cross-tile QK^T/softmax ping-pong.
// Q must be pre-scaled by 0.125*log2(e) (folded into projection).
// ---------------------------------------------------------------------------
__global__ __launch_bounds__(512) void attn_mfma_kernel(
        const __bf16* __restrict__ q, const __bf16* __restrict__ k,
        const __bf16* __restrict__ v, __bf16* __restrict__ o,
        int Nq, int Nk, int sq, int skv) {
    __shared__ __attribute__((aligned(16))) __bf16 Ks[2][4096];  // [key][64d] swz
    __shared__ __attribute__((aligned(16))) __bf16 Vt[2][4096];  // [dim][64key] swz
    __shared__ __attribute__((aligned(16))) __bf16 Pl[8][1024];  // per-wave [qrow][64key]

    int tid = threadIdx.x;
    int w = tid >> 6, lane = tid & 63;
    int r = lane & 15, g = lane >> 4;
    int rx = r & 7;

    int nqb = Nq >> 7;
    int qb = blockIdx.x % nqb;
    int hh = (blockIdx.x / nqb) % NHEADS;
    int b  = blockIdx.x / (nqb * NHEADS);

    const __bf16* qp = q + ((size_t)(b * Nq + (qb << 7) + (w << 4) + r)) * sq
                         + hh * DHEAD + (g << 3);
    bf16x8 qf0 = *(const bf16x8*)qp;
    bf16x8 qf1 = *(const bf16x8*)(qp + 32);

    // staging roles
    bool isK = (tid >= 256);
    int sidx = tid & 255;
    int krow = sidx >> 2, kp_ = sidx & 3;
    int va = sidx & 31, vbb = sidx >> 5;
    size_t kvbase = (size_t)b * Nk * skv + (size_t)hh * DHEAD;
    const __bf16* kp = k + kvbase + (size_t)krow * skv + (kp_ << 4);
    const __bf16* vp = v + kvbase + (size_t)(2 * va) * skv + (vbb << 3);
    int kwo0 = krow * 64 + ((((kp_ << 1) | 0) ^ (krow & 7)) << 3);
    int kwo1 = krow * 64 + ((((kp_ << 1) | 1) ^ (krow & 7)) << 3);
    int vwb  = vbb * 512 + ((va & 3) << 1);

    f32x4 oacc[4];
#pragma unroll
    for (int dt = 0; dt < 4; ++dt) oacc[dt] = (f32x4){0.f, 0.f, 0.f, 0.f};
    float m = -1e30f, l = 0.f;
    f32x4 saccA[4], saccB[4];
    bf16x8 sr0, sr1;            // staging regs (K halves or V dim-rows by role)
    bf16x8 vf[2][4], pa[2];

    auto LOADREG = [&](int t) {
        if (isK) {
            const __bf16* kp2 = kp + (size_t)t * 64 * skv;
            sr0 = *(const bf16x8*)kp2; sr1 = *(const bf16x8*)(kp2 + 8);
        } else {
            const __bf16* vp2 = vp + (size_t)t * 64 * skv;
            sr0 = *(const bf16x8*)vp2; sr1 = *(const bf16x8*)(vp2 + skv);
        }
    };
    auto STAGEW = [&](int buf) {
        if (isK) {
            *(bf16x8*)&Ks[buf][kwo0] = sr0;
            *(bf16x8*)&Ks[buf][kwo1] = sr1;
        } else {
#pragma unroll
            for (int j = 0; j < 8; ++j) {
                bf16x2 pr; pr[0] = sr0[j]; pr[1] = sr1[j];
                *(bf16x2*)&Vt[buf][vwb + j * 64 + (((va >> 2) ^ j) << 3)] = pr;
            }
        }
    };
    auto QKT = [&](f32x4 (&sacc)[4], int buf) {
#pragma unroll
        for (int nt = 0; nt < 4; ++nt) sacc[nt] = (f32x4){0.f, 0.f, 0.f, 0.f};
        __builtin_amdgcn_s_setprio(1);
#pragma unroll
        for (int nt = 0; nt < 4; ++nt) {
            bf16x8 kf0 = *(const bf16x8*)&Ks[buf][((nt << 4) + r) * 64 + ((g ^ rx) << 3)];
            bf16x8 kf1 = *(const bf16x8*)&Ks[buf][((nt << 4) + r) * 64 + (((g + 4) ^ rx) << 3)];
            sacc[nt] = __builtin_amdgcn_mfma_f32_16x16x32_bf16(kf0, qf0, sacc[nt], 0, 0, 0);
            sacc[nt] = __builtin_amdgcn_mfma_f32_16x16x32_bf16(kf1, qf1, sacc[nt], 0, 0, 0);
        }
        __builtin_amdgcn_s_setprio(0);
    };
    auto SMAX = [&](f32x4 (&sacc)[4]) {
        float mx = sacc[0][0];
#pragma unroll
        for (int nt = 0; nt < 4; ++nt)
#pragma unroll
            for (int rg = 0; rg < 4; ++rg) mx = fmaxf(mx, sacc[nt][rg]);
        mx = fmaxf(mx, __shfl_xor(mx, 16));
        mx = fmaxf(mx, __shfl_xor(mx, 32));
        if (!__all(mx <= m + DEFER_THR)) {
            float mn = fmaxf(m, mx);
            float al = exp2f(m - mn);
            m = mn; l *= al;
#pragma unroll
            for (int dt = 0; dt < 4; ++dt)
#pragma unroll
                for (int rg = 0; rg < 4; ++rg) oacc[dt][rg] *= al;
        }
        float sum = 0.f;
#pragma unroll
        for (int nt = 0; nt < 4; ++nt) {
            bf16x4 pk;
#pragma unroll
            for (int rg = 0; rg < 4; ++rg) {
                float p = exp2f(sacc[nt][rg] - m);
                sum += p;
                pk[rg] = (__bf16)p;
            }
            *(bf16x4*)&Pl[w][r * 64 + ((((nt << 1) | (g >> 1)) ^ rx) << 3) + ((g & 1) << 2)] = pk;
        }
        l += sum;   // per-lane partial; reduced across g-lanes in epilogue
    };
    auto VFLOAD = [&](int buf) {
#pragma unroll
        for (int kh = 0; kh < 2; ++kh) {
            pa[kh] = *(const bf16x8*)&Pl[w][r * 64 + ((((kh << 2) + g) ^ rx) << 3)];
#pragma unroll
            for (int dt = 0; dt < 4; ++dt)
                vf[kh][dt] = *(const bf16x8*)&Vt[buf][((dt << 4) + r) * 64
                                                      + ((((kh << 2) + g) ^ rx) << 3)];
        }
    };
    auto PVOP = [&]() {
        __builtin_amdgcn_s_setprio(1);
#pragma unroll
        for (int kh = 0; kh < 2; ++kh)
#pragma unroll
            for (int dt = 0; dt < 4; ++dt)
                oacc[dt] = __builtin_amdgcn_mfma_f32_16x16x32_bf16(
                    vf[kh][dt], pa[kh], oacc[dt], 0, 0, 0);
        __builtin_amdgcn_s_setprio(0);
    };

    int ntiles = Nk >> 6;   // always even (>=2) for our shapes
    // ---- prologue ----------------------------------------------------------
    LOADREG(0);
    STAGEW(0);
    LOADREG(1);
    __syncthreads();
    QKT(saccA, 0);

    for (int t = 0; t + 1 < ntiles; t += 2) {
        // ---- even phase: tile t (buf0, saccA); regs hold t+1 ----------------
        STAGEW(1);
        if (t + 2 < ntiles) LOADREG(t + 2);
        SMAX(saccA);
        VFLOAD(0);
        __syncthreads();
        QKT(saccB, 1);
        PVOP();
        // ---- odd phase: tile t+1 (buf1, saccB); regs hold t+2 ---------------
        if (t + 2 < ntiles) {
            STAGEW(0);
            if (t + 3 < ntiles) LOADREG(t + 3);
        }
        SMAX(saccB);
        VFLOAD(1);
        __syncthreads();
        if (t + 2 < ntiles) QKT(saccA, 0);
        PVOP();
    }

    // ---- epilogue: reduce l across g-lanes, write O^T/l --------------------
    l += __shfl_xor(l, 16);
    l += __shfl_xor(l, 32);
    float inv = 1.0f / l;
    __bf16* ob = o + ((size_t)(b * Nq + (qb << 7) + (w << 4) + r)) * D_MODEL + hh * DHEAD;
#pragma unroll
    for (int dt = 0; dt < 4; ++dt) {
        bf16x4 ov;
#pragma unroll
        for (int rg = 0; rg < 4; ++rg) ov[rg] = (__bf16)(oacc[dt][rg] * inv);
        *(bf16x4*)&ob[(dt << 4) + (g << 2)] = ov;
    }
}

// ---------------------------------------------------------------------------
extern "C" void kernel_launch(void* const* d_in, const int* in_sizes, int n_in,
                              void* d_out, int out_size, void* d_ws, size_t ws_size,
                              hipStream_t stream) {
    const float* x    = (const float*)d_in[0];
    const float* t    = (const float*)d_in[1];
    const float* cond = (const float*)d_in[2];
    const float* n1_w = (const float*)d_in[3];
    const float* n1_b = (const float*)d_in[4];
    const float* n2_w = (const float*)d_in[5];
    const float* n2_b = (const float*)d_in[6];
    const float* n4_w = (const float*)d_in[7];
    const float* n4_b = (const float*)d_in[8];
    const float* a1_q = (const float*)d_in[9];
    const float* a1_k = (const float*)d_in[10];
    const float* a1_v = (const float*)d_in[11];
    const float* a1_o = (const float*)d_in[12];
    const float* a1_ob= (const float*)d_in[13];
    const float* a2_q = (const float*)d_in[14];
    const float* a2_k = (const float*)d_in[15];
    const float* a2_v = (const float*)d_in[16];
    const float* a2_o = (const float*)d_in[17];
    const float* a2_ob= (const float*)d_in[18];
    const float* ff_w1= (const float*)d_in[19];
    const float* ff_b1= (const float*)d_in[20];
    const float* ff_w2= (const float*)d_in[21];
    const float* ff_b2= (const float*)d_in[22];
    float* out = (float*)d_out;

    const int B  = in_sizes[1] / D_MODEL;              // 2
    const int N  = in_sizes[0] / (B * D_MODEL);        // 2048
    const int Nc = in_sizes[2] / (B * D_MODEL);        // 1024
    const int R  = B * N;                              // 4096
    const int Rc = B * Nc;                             // 2048

    // ---- workspace layout (~32.3 MB) -----------------------------------------
    char* Wb = (char*)d_ws;
    float* emb   = (float*)Wb;                                   // 32 KB
    __bf16* r1   = (__bf16*)(Wb + 32768);                        // 16 MB region
    __bf16* qkv  = r1;                                           // [R][1536]
    __bf16* q2   = r1;                                           // [R][512]
    __bf16* kv2  = r1 + (size_t)R * 512;                         // [Rc][1024]
    __bf16* gg   = r1;                                           // [R][2048]
    __bf16* h_bf = (__bf16*)(Wb + 32768 + 16777216);             // 4 MB
    __bf16* c_bf = (__bf16*)(Wb + 32768 + 16777216 + 4194304);   // 2 MB
    __bf16* wts  = (__bf16*)(Wb + 32768 + 16777216 + 4194304 + 2097152);
    __bf16* a1_qt = wts;                      // contiguous q,k,v -> fused QKV Bt
    __bf16* a1_ot = wts + 3 * 262144;
    __bf16* a2_qt = wts + 4 * 262144;
    __bf16* a2_kt = wts + 5 * 262144;         // contiguous k,v -> fused KV Bt
    __bf16* a2_ot = wts + 7 * 262144;
    __bf16* ff1t  = wts + 8 * 262144;         // [4096][512]
    __bf16* ff2t  = ff1t + 2097152;           // [512][2048]

    dim3 blk(256);

    // ---- single merged prep dispatch -------------------------------------------
    PrepArgs pa;
    pa.t = t; pa.n1w = n1_w; pa.n1b = n1_b; pa.n2w = n2_w; pa.n2b = n2_b;
    pa.n4w = n4_w; pa.n4b = n4_b; pa.emb = emb;
    pa.ws[0] = a1_q; pa.ws[1] = a1_k; pa.ws[2] = a1_v; pa.ws[3] = a1_o;
    pa.ws[4] = a2_q; pa.ws[5] = a2_k; pa.ws[6] = a2_v; pa.ws[7] = a2_o;
    pa.wd[0] = a1_qt; pa.wd[1] = wts + 262144; pa.wd[2] = wts + 2 * 262144; pa.wd[3] = a1_ot;
    pa.wd[4] = a2_qt; pa.wd[5] = a2_kt; pa.wd[6] = wts + 6 * 262144; pa.wd[7] = a2_ot;
    pa.ffw1 = ff_w1; pa.ffw2 = ff_w2; pa.ff1t = ff1t; pa.ff2t = ff2t;
    pa.cond = cond; pa.cbf = c_bf; pa.B = B; pa.condN = Rc * D_MODEL;
    prep_kernel<<<dim3(1304 + (Rc * D_MODEL) / 1024), blk, 0, stream>>>(pa);

    // ---- block 1: self-attention -----------------------------------------------
    adaln_apply_kernel<<<dim3(R), blk, 0, stream>>>(x, emb, h_bf, N);
    gemm_bf16_kernel<2, 64><<<dim3(24, R / 128), blk, 0, stream>>>(
        h_bf, a1_qt, nullptr, nullptr, qkv, R, 512, 1536);
    attn_mfma_kernel<<<dim3(B * NHEADS * (N / 128)), dim3(512), 0, stream>>>(
        qkv, qkv + 512, qkv + 1024, h_bf, N, N, 1536, 1536);
    gemm_bf16_kernel<1, 32><<<dim3(8, R / 64), blk, 0, stream>>>(
        h_bf, a1_ot, a1_ob, x, out, R, 512, 512);

    // ---- block 2: cross-attention ------------------------------------------------
    adaln_apply_kernel<<<dim3(R), blk, 0, stream>>>(
        out, emb + (size_t)B * 2 * D_MODEL, h_bf, N);
    gemm_dual_kernel<<<dim3(8 * (R / 64) + 16 * (Rc / 64)), blk, 0, stream>>>(
        h_bf, a2_qt, q2, R, c_bf, a2_kt, kv2, Rc);
    attn_mfma_kernel<<<dim3(B * NHEADS * (N / 128)), dim3(512), 0, stream>>>(
        q2, kv2, kv2 + 512, h_bf, N, Nc, 512, 1024);
    gemm_bf16_kernel<1, 32><<<dim3(8, R / 64), blk, 0, stream>>>(
        h_bf, a2_ot, a2_ob, out, out, R, 512, 512);

    // ---- GEGLU feed-forward ---------------------------------------------------------
    adaln_apply_kernel<<<dim3(R), blk, 0, stream>>>(
        out, emb + (size_t)2 * B * 2 * D_MODEL, h_bf, N);
    gemm_geglu_bf16_kernel<<<dim3(32, R / 128), blk, 0, stream>>>(
        h_bf, ff1t, ff_b1, gg, R, 512);
    gemm_bf16_kernel<1, 32><<<dim3(8, R / 64), blk, 0, stream>>>(
        gg, ff2t, ff_b2, out, out, R, 2048, 512);
}